// Round 1
// baseline (21669.313 us; speedup 1.0000x reference)
//
#include <hip/hip_runtime.h>

#define BB 16
#define TT 1024
#define FF 128
#define RR 2048
#define HALFR 1024
#define NBLK 256
#define NTHR 512

// ---- coherent store (write-through to IC) + vm drain ----
__device__ __forceinline__ void stg_sc1(float* base, unsigned voff, float v) {
    asm volatile("global_store_dword %0, %1, %2 sc0 sc1"
                 :: "v"(voff), "v"(v), "s"(base) : "memory");
}
__device__ __forceinline__ void wait_vm0() {
    asm volatile("s_waitcnt vmcnt(0)" ::: "memory");
}

// ---------------- init: h0 + barrier words ----------------
__global__ void init_state_kernel(float* __restrict__ h, const float* __restrict__ start,
                                  unsigned* __restrict__ bar) {
    int idx = blockIdx.x * blockDim.x + threadIdx.x;
    if (idx < BB * RR) h[idx] = start[idx & (RR - 1)];
    if (idx < 2048) bar[idx] = 0u;
}

// ---------------- persistent fp32 ESN kernel ----------------
// R11 (two coupled changes vs R10):
//  (a) W_rec moves LDS -> registers. Waves repartition as 4 k-slices x 2
//      batch-groups: wave (ks,bg) holds W[8 rows][512 k] in 64 VGPR
//      (loaded once, reused all 1024 steps) and computes acc[8r][8b] over
//      its k-slice. Eliminates the 512 ds_read_b128/CU/step (~1.8us) that
//      bounded the MAC. Fold: 6-level select-fold (126 shfl), lane L ends
//      holding the full (r=L>>3, b=L&7) sum; 4-way cross-wave reduce via
//      2KB LDS. LDS total 68KB -> 6KB.
//  (b) h broadcast via CACHED loads + per-step agent acquire fence
//      (buffer_inv sc1) instead of sc0sc1 IC loads. Stores stay sc0sc1 +
//      vmcnt(0) before barrier arrival (release side unchanged), so the
//      fence-invalidate at loop top guarantees fresh h from IC on first
//      touch; the 32 blocks of each XCD then share h lines in L2:
//      IC reads 32MB -> ~1MB per step, latency ~700 -> ~250 cyc.
// Barrier: R5 two-level all-relaxed RMW scheme, byte-for-byte.
__global__ __launch_bounds__(NTHR, 2) void esn_f32(
    const float* __restrict__ inputs,   // [B,T,F]
    const float* __restrict__ Win,      // [R,F]
    const float* __restrict__ Wrec,     // [R,R]
    const float* __restrict__ bias,     // [R]
    float* __restrict__ hA,             // [B,R]
    float* __restrict__ hB,             // [B,R]
    float* __restrict__ out,            // [B,T,HALFR]
    unsigned* __restrict__ bar)
{
    __shared__ __align__(16) float sWin[8][FF];   // 4 KB
    __shared__ float sRed[8][64];                 // 2 KB

    const int tid  = threadIdx.x;
    const int lane = tid & 63;
    const int wave = tid >> 6;          // 0..7
    const int bg   = wave & 1;          // batch group: batches bg*8 .. bg*8+7
    const int ks   = wave >> 1;         // k-slice:     ks*512 .. ks*512+511
    const int r0b  = blockIdx.x * 8;
    const bool projb = (r0b < HALFR);

    // Stage Win into LDS once (read per step by proj lanes).
    {
        const float4* wis = (const float4*)(Win + (size_t)r0b * FF);
        float4* wid = (float4*)sWin;
        for (int i = tid; i < (8 * FF) / 4; i += NTHR) wid[i] = wis[i];
    }

    // W_rec -> registers: wreg[r][j] = W[r0b+r][ks*512 + j*256 + lane*4 ..+3]
    const int kb = ks * 512 + lane * 4;
    float4 wreg[8][2];
#pragma unroll
    for (int r = 0; r < 8; ++r) {
        const float* wp = Wrec + (size_t)(r0b + r) * RR + kb;
        wreg[r][0] = *(const float4*)(wp);
        wreg[r][1] = *(const float4*)(wp + 256);
    }
    __syncthreads();

    const int bbase = bg * 8;                   // first batch of this wave
    const int fl    = ks * 32 + (lane & 31);    // proj f (lanes<32): 4 ks-waves cover f=0..127
    const bool hi32 = (lane & 32) != 0;
    const bool hi16 = (lane & 16) != 0;
    const bool hi8  = (lane & 8)  != 0;
    const bool hi4  = (lane & 4)  != 0;
    const bool hi2  = (lane & 2)  != 0;
    const bool hi1  = (lane & 1)  != 0;

    // Epilogue mapping (tid < 128): fold output lane L holds (r=L>>3, b=L&7).
    const int ebg = tid >> 6, eL = tid & 63;
    const int er  = r0b + (eL >> 3);
    const int eB  = ebg * 8 + (eL & 7);
    const float myBias = bias[er];
    const unsigned eOff = (unsigned)((eB * RR + er) * 4);   // used only when tid<128

    // R5 two-level barrier state (all-relaxed; each word on its own 128B line).
    const unsigned g = blockIdx.x & 15u;
    unsigned* grpCnt      = bar + g * 32;
    unsigned* masterCnt   = bar + 16 * 32;
    unsigned* masterEpoch = bar + 17 * 32;
    unsigned* grpEpoch    = bar + (18 + g) * 32;

    for (int t = 0; t < TT; ++t) {
        // Invalidate L1/L2 so cached h loads observe other XCDs' sc-stores
        // (also covers t=0 against stale lines from earlier launches).
        __builtin_amdgcn_fence(__ATOMIC_ACQUIRE, "agent");

        const float* hc = (t & 1) ? hB : hA;
        float*       hn = (t & 1) ? hA : hB;

        // 1) Issue all 16 cached h loads (L2-shared within each XCD).
        float4 hbuf[8][2];
#pragma unroll
        for (int b = 0; b < 8; ++b) {
            const float* p = hc + (size_t)(bbase + b) * RR + kb;
            hbuf[b][0] = *(const float4*)(p);
            hbuf[b][1] = *(const float4*)(p + 256);
        }

        float acc[8][8];
#pragma unroll
        for (int r = 0; r < 8; ++r)
#pragma unroll
            for (int b = 0; b < 8; ++b) acc[r][b] = 0.0f;

        // 2) Input projection overlaps h-load latency. Wave (ks,bg) lanes<32
        //    cover f = ks*32 + lane for its 8 batches; cross-wave reduce sums
        //    the 4 ks-slices -> full f=0..127 coverage per (r, batch).
        if (projb && lane < 32) {
            float xv[8];
#pragma unroll
            for (int b = 0; b < 8; ++b)
                xv[b] = inputs[((size_t)(bbase + b) * TT + t) * FF + fl];
#pragma unroll
            for (int r = 0; r < 8; ++r) {
                const float wv = sWin[r][fl];
#pragma unroll
                for (int b = 0; b < 8; ++b)
                    acc[r][b] = fmaf(wv, xv[b], acc[r][b]);
            }
        }

        // 3) MAC: W from registers, h from the cached prefetch. 512 FMA/lane.
#pragma unroll
        for (int r = 0; r < 8; ++r)
#pragma unroll
            for (int b = 0; b < 8; ++b) {
                float a = acc[r][b];
                a = fmaf(wreg[r][0].x, hbuf[b][0].x, a);
                a = fmaf(wreg[r][0].y, hbuf[b][0].y, a);
                a = fmaf(wreg[r][0].z, hbuf[b][0].z, a);
                a = fmaf(wreg[r][0].w, hbuf[b][0].w, a);
                a = fmaf(wreg[r][1].x, hbuf[b][1].x, a);
                a = fmaf(wreg[r][1].y, hbuf[b][1].y, a);
                a = fmaf(wreg[r][1].z, hbuf[b][1].z, a);
                a = fmaf(wreg[r][1].w, hbuf[b][1].w, a);
                acc[r][b] = a;
            }

        // 4) Fold 64 values -> 1/lane. Level d moves index-bit into lane-bit d;
        //    after d=32..1, lane L holds the full-wave sum for index i = L
        //    (i = r*8+b). Each level: B[i] = (lane&d) ? A[i+n/2]+shfl(A[i+n/2],d)
        //                                             : A[i]    +shfl(A[i],d).
        float e;
        {
            float s32v[32];
#pragma unroll
            for (int i = 0; i < 32; ++i) {
                const float A  = acc[i >> 3][i & 7];
                const float Bv = acc[(i >> 3) + 4][i & 7];
                const float u  = __shfl_xor(A, 32);
                const float w2 = __shfl_xor(Bv, 32);
                s32v[i] = hi32 ? (Bv + w2) : (A + u);
            }
            float s16v[16];
#pragma unroll
            for (int i = 0; i < 16; ++i) {
                const float u  = __shfl_xor(s32v[i], 16);
                const float w2 = __shfl_xor(s32v[i + 16], 16);
                s16v[i] = hi16 ? (s32v[i + 16] + w2) : (s32v[i] + u);
            }
            float s8v[8];
#pragma unroll
            for (int i = 0; i < 8; ++i) {
                const float u  = __shfl_xor(s16v[i], 8);
                const float w2 = __shfl_xor(s16v[i + 8], 8);
                s8v[i] = hi8 ? (s16v[i + 8] + w2) : (s16v[i] + u);
            }
            float s4v[4];
#pragma unroll
            for (int i = 0; i < 4; ++i) {
                const float u  = __shfl_xor(s8v[i], 4);
                const float w2 = __shfl_xor(s8v[i + 4], 4);
                s4v[i] = hi4 ? (s8v[i + 4] + w2) : (s8v[i] + u);
            }
            float s2v[2];
#pragma unroll
            for (int i = 0; i < 2; ++i) {
                const float u  = __shfl_xor(s4v[i], 2);
                const float w2 = __shfl_xor(s4v[i + 2], 2);
                s2v[i] = hi2 ? (s4v[i + 2] + w2) : (s4v[i] + u);
            }
            const float u  = __shfl_xor(s2v[0], 1);
            const float w2 = __shfl_xor(s2v[1], 1);
            e = hi1 ? (s2v[1] + w2) : (s2v[0] + u);
        }

        // 5) Cross-wave reduce (4 k-slices per batch-group) + epilogue.
        sRed[wave][lane] = e;
        __syncthreads();
        if (tid < 128) {
            const float val = sRed[ebg][eL] + sRed[2 + ebg][eL] +
                              sRed[4 + ebg][eL] + sRed[6 + ebg][eL];
            const float pre  = val + myBias;
            const float hold = hc[(size_t)eB * RR + er];   // cache-hot (loaded this step)
            const float vnew = 0.05f * hold + 0.95f * tanhf(pre);
            stg_sc1(hn, eOff, vnew);
            if (r0b >= HALFR)
                out[((size_t)eB * TT + t) * HALFR + (er - HALFR)] = vnew;
        }

        // 6) Drain stores, block-sync, R5 two-level all-relaxed grid barrier.
        wait_vm0();
        __syncthreads();
        if (tid == 0) {
            const unsigned tgt = (unsigned)(t + 1);
            const unsigned old = __hip_atomic_fetch_add(grpCnt, 1u, __ATOMIC_RELAXED,
                                                        __HIP_MEMORY_SCOPE_AGENT);
            if (old == tgt * 16u - 1u) {                   // last arriver in group
                const unsigned mo = __hip_atomic_fetch_add(masterCnt, 1u, __ATOMIC_RELAXED,
                                                           __HIP_MEMORY_SCOPE_AGENT);
                if (mo == tgt * 16u - 1u) {                // last group overall
                    __hip_atomic_store(masterEpoch, tgt, __ATOMIC_RELAXED,
                                       __HIP_MEMORY_SCOPE_AGENT);
                } else {
                    while (__hip_atomic_load(masterEpoch, __ATOMIC_RELAXED,
                                             __HIP_MEMORY_SCOPE_AGENT) < tgt)
                        __builtin_amdgcn_s_sleep(2);
                }
                __hip_atomic_store(grpEpoch, tgt, __ATOMIC_RELAXED,
                                   __HIP_MEMORY_SCOPE_AGENT);
            } else {
                while (__hip_atomic_load(grpEpoch, __ATOMIC_RELAXED,
                                         __HIP_MEMORY_SCOPE_AGENT) < tgt)
                    __builtin_amdgcn_s_sleep(2);
            }
        }
        __syncthreads();
    }
}

// ---------------- fallback path (proven R1): fp32, 1024 launches ----------------

__global__ void init_h_kernel(float* __restrict__ h, const float* __restrict__ start) {
    int idx = blockIdx.x * blockDim.x + threadIdx.x;
    if (idx < BB * RR) h[idx] = start[idx & (RR - 1)];
}

__global__ __launch_bounds__(512, 2) void step_kernel(
    const float* __restrict__ inputs, const float* __restrict__ Win,
    const float* __restrict__ Wrec, const float* __restrict__ bias,
    const float* __restrict__ h_cur, float* __restrict__ h_next,
    float* __restrict__ out, int t)
{
    const int tid  = threadIdx.x;
    const int wave = tid >> 6;
    const int half = (tid >> 5) & 1;
    const int kl   = tid & 31;
    const int b    = wave * 2 + half;
    const int r0   = blockIdx.x * 8;

    float acc[8];
#pragma unroll
    for (int r = 0; r < 8; ++r) acc[r] = 0.0f;

    if (r0 < HALFR) {
        const float4 in4 = *reinterpret_cast<const float4*>(
            inputs + ((size_t)b * TT + t) * FF + kl * 4);
#pragma unroll
        for (int r = 0; r < 8; ++r) {
            const float4 w4 = *reinterpret_cast<const float4*>(
                Win + (size_t)(r0 + r) * FF + kl * 4);
            acc[r] += in4.x * w4.x + in4.y * w4.y + in4.z * w4.z + in4.w * w4.w;
        }
    }

    const float* hb = h_cur + (size_t)b * RR;
#pragma unroll 2
    for (int j = 0; j < 16; ++j) {
        const int k = kl * 4 + j * 128;
        const float4 h4 = *reinterpret_cast<const float4*>(hb + k);
#pragma unroll
        for (int r = 0; r < 8; ++r) {
            const float4 w4 = *reinterpret_cast<const float4*>(
                Wrec + (size_t)(r0 + r) * RR + k);
            acc[r] = fmaf(h4.x, w4.x, acc[r]);
            acc[r] = fmaf(h4.y, w4.y, acc[r]);
            acc[r] = fmaf(h4.z, w4.z, acc[r]);
            acc[r] = fmaf(h4.w, w4.w, acc[r]);
        }
    }

#pragma unroll
    for (int r = 0; r < 8; ++r) {
        float v = acc[r];
        v += __shfl_xor(v, 1);  v += __shfl_xor(v, 2);
        v += __shfl_xor(v, 4);  v += __shfl_xor(v, 8);
        v += __shfl_xor(v, 16);
        acc[r] = v;
    }

    __shared__ float red[BB][8];
    if (kl == 0) {
#pragma unroll
        for (int r = 0; r < 8; ++r) red[b][r] = acc[r];
    }
    __syncthreads();

    if (tid < BB * 8) {
        const int rr = tid & 7, bb = tid >> 3;
        const int r  = r0 + rr;
        const float pre = red[bb][rr] + bias[r];
        const float h_old = h_cur[(size_t)bb * RR + r];
        const float hn = 0.05f * h_old + 0.95f * tanhf(pre);
        h_next[(size_t)bb * RR + r] = hn;
        if (r0 >= HALFR) out[((size_t)bb * TT + t) * HALFR + (r - HALFR)] = hn;
    }
}

// ---------------- launch ----------------

extern "C" void kernel_launch(void* const* d_in, const int* in_sizes, int n_in,
                              void* d_out, int out_size, void* d_ws, size_t ws_size,
                              hipStream_t stream) {
    const float* inputs = (const float*)d_in[0];   // [B,T,F]
    const float* Win    = (const float*)d_in[1];   // [R,F]
    const float* Wrec   = (const float*)d_in[2];   // [R,R]
    const float* bias   = (const float*)d_in[3];   // [R]
    const float* start  = (const float*)d_in[4];   // [R]
    float* out = (float*)d_out;                    // [B,T,HALFR]

    float* hA = (float*)d_ws;                      // [B,R] fp32
    float* hB = hA + (size_t)BB * RR;              // [B,R] fp32
    unsigned* bar = (unsigned*)(hB + (size_t)BB * RR);
    const size_t need = (size_t)BB * RR * 4 * 2 + 8192;

    if (ws_size >= need) {
        init_state_kernel<<<64, 512, 0, stream>>>(hA, start, bar);
        void* args[] = { (void*)&inputs, (void*)&Win, (void*)&Wrec, (void*)&bias,
                         (void*)&hA, (void*)&hB, (void*)&out, (void*)&bar };
        hipLaunchCooperativeKernel((void*)esn_f32, dim3(NBLK), dim3(NTHR),
                                   args, 0, stream);
    } else {
        init_h_kernel<<<(BB * RR + 255) / 256, 256, 0, stream>>>(hA, start);
        for (int t = 0; t < TT; ++t) {
            const float* hc = (t & 1) ? hB : hA;
            float*       hn = (t & 1) ? hA : hB;
            step_kernel<<<256, 512, 0, stream>>>(inputs, Win, Wrec, bias, hc, hn, out, t);
        }
    }
}

// Round 3
// 7608.300 us; speedup vs baseline: 2.8481x; 2.8481x over previous
//
#include <hip/hip_runtime.h>

#define BB 16
#define TT 1024
#define FF 128
#define RR 2048
#define HALFR 1024
#define NBLK 256
#define NTHR 512

// ---- coherent (IC-level) memory ops: bypass L1/L2, no fences needed ----
__device__ __forceinline__ float4 ldg_sc4(const float* base, unsigned voff) {
    float4 r;
    asm volatile("global_load_dwordx4 %0, %1, %2 sc0 sc1"
                 : "=v"(r) : "v"(voff), "s"(base) : "memory");
    return r;
}
__device__ __forceinline__ float ldg_sc1(const float* base, unsigned voff) {
    float r;
    asm volatile("global_load_dword %0, %1, %2 sc0 sc1"
                 : "=v"(r) : "v"(voff), "s"(base) : "memory");
    return r;
}
__device__ __forceinline__ void stg_sc1(float* base, unsigned voff, float v) {
    asm volatile("global_store_dword %0, %1, %2 sc0 sc1"
                 :: "v"(voff), "v"(v), "s"(base) : "memory");
}
__device__ __forceinline__ void wait_vm0() {
    asm volatile("s_waitcnt vmcnt(0)" ::: "memory");
}

// ---------------- init: h0 + barrier words ----------------
__global__ void init_state_kernel(float* __restrict__ h, const float* __restrict__ start,
                                  unsigned* __restrict__ bar) {
    int idx = blockIdx.x * blockDim.x + threadIdx.x;
    if (idx < BB * RR) h[idx] = start[idx & (RR - 1)];
    if (idx < 2048) bar[idx] = 0u;
}

// ---------------- persistent fp32 ESN kernel ----------------
// R13 = union of two PROVEN-PASSING pieces, nothing else:
//  - Compute structure: R11 byte-for-byte (correctness-verified, absmax
//    identical to R10): W_rec register-resident (wave = 4 k-slices x 2
//    batch-groups, lane holds W[8r][8k] in 64 VGPR), acc[8r][8b],
//    6-level select-fold (lane L ends with (r=L>>3,b=L&7)), 4-way
//    cross-wave LDS reduce, tid<128 epilogue.
//  - h path: R10 byte-for-byte mechanics (proven at 6276us): sc0sc1 IC
//    loads via 16 INDIVIDUALLY precomputed voffsets (no offset: imm —
//    that was new in the crashed R12), hold loaded UNCONDITIONALLY with
//    an all-threads-valid clamped offset (as in R10), single vmcnt(0)
//    drain.  NEW safety per guide rule #18: sched_barrier(0) right after
//    the drain so hipcc cannot hoist hbuf-consuming FMAs above it.
//  - NO per-step fence (R11's buffer_inv = 3.4x regression).
// Barrier: R5 two-level all-relaxed RMW scheme, byte-for-byte.
__global__ __launch_bounds__(NTHR, 2) void esn_f32(
    const float* __restrict__ inputs,   // [B,T,F]
    const float* __restrict__ Win,      // [R,F]
    const float* __restrict__ Wrec,     // [R,R]
    const float* __restrict__ bias,     // [R]
    float* __restrict__ hA,             // [B,R]
    float* __restrict__ hB,             // [B,R]
    float* __restrict__ out,            // [B,T,HALFR]
    unsigned* __restrict__ bar)
{
    __shared__ __align__(16) float sWin[8][FF];   // 4 KB
    __shared__ float sRed[8][64];                 // 2 KB

    const int tid  = threadIdx.x;
    const int lane = tid & 63;
    const int wave = tid >> 6;          // 0..7
    const int bg   = wave & 1;          // batch group: batches bg*8 .. bg*8+7
    const int ks   = wave >> 1;         // k-slice:     ks*512 .. ks*512+511
    const int r0b  = blockIdx.x * 8;
    const bool projb = (r0b < HALFR);

    // Stage Win into LDS once (read per step by proj lanes).
    {
        const float4* wis = (const float4*)(Win + (size_t)r0b * FF);
        float4* wid = (float4*)sWin;
        for (int i = tid; i < (8 * FF) / 4; i += NTHR) wid[i] = wis[i];
    }

    // W_rec -> registers: wreg[r][j] = W[r0b+r][ks*512 + j*256 + lane*4 ..+3]
    const int kb = ks * 512 + lane * 4;
    float4 wreg[8][2];
#pragma unroll
    for (int r = 0; r < 8; ++r) {
        const float* wp = Wrec + (size_t)(r0b + r) * RR + kb;
        wreg[r][0] = *(const float4*)(wp);
        wreg[r][1] = *(const float4*)(wp + 256);
    }
    __syncthreads();

    const int bbase = bg * 8;                   // first batch of this wave
    const int fl    = ks * 32 + (lane & 31);    // proj f (lanes<32): 4 ks-waves cover f=0..127
    const bool hi32 = (lane & 32) != 0;
    const bool hi16 = (lane & 16) != 0;
    const bool hi8  = (lane & 8)  != 0;
    const bool hi4  = (lane & 4)  != 0;
    const bool hi2  = (lane & 2)  != 0;
    const bool hi1  = (lane & 1)  != 0;

    // Coherent h-load byte offsets: 16 individually precomputed (R10 style).
    unsigned voffH[8][2];
#pragma unroll
    for (int b = 0; b < 8; ++b) {
#pragma unroll
        for (int j = 0; j < 2; ++j)
            voffH[b][j] = (unsigned)((((bbase + b) * RR) + kb + j * 256) * 4);
    }

    // Epilogue mapping: fold output lane L holds (r=L>>3, b=L&7); only
    // tid<128 writes, but the hold-load offset is valid for ALL threads
    // (eB clamped) so the load can be unconditional like R10's.
    const int ebg = tid >> 6, eL = tid & 63;
    const int er  = r0b + (eL >> 3);
    const int eB  = ebg * 8 + (eL & 7);              // 0..15 for tid<128
    const int eBc = (tid < 128) ? eB : 0;            // clamp for safety
    const float myBias = bias[er];
    const unsigned eOff = (unsigned)((eBc * RR + er) * 4);

    // R5 two-level barrier state (all-relaxed; each word on its own 128B line).
    const unsigned g = blockIdx.x & 15u;
    unsigned* grpCnt      = bar + g * 32;
    unsigned* masterCnt   = bar + 16 * 32;
    unsigned* masterEpoch = bar + 17 * 32;
    unsigned* grpEpoch    = bar + (18 + g) * 32;

    for (int t = 0; t < TT; ++t) {
        const float* hc = (t & 1) ? hB : hA;
        float*       hn = (t & 1) ? hA : hB;

        // 1) Issue ALL coherent h loads up front (16 + 1 in flight, R10 style).
        float4 hbuf[8][2];
#pragma unroll
        for (int b = 0; b < 8; ++b) {
            hbuf[b][0] = ldg_sc4(hc, voffH[b][0]);
            hbuf[b][1] = ldg_sc4(hc, voffH[b][1]);
        }
        const float hold = ldg_sc1(hc, eOff);

        float acc[8][8];
#pragma unroll
        for (int r = 0; r < 8; ++r)
#pragma unroll
            for (int b = 0; b < 8; ++b) acc[r][b] = 0.0f;

        // 2) Input projection overlaps h-load latency. Wave (ks,bg) lanes<32
        //    cover f = ks*32 + lane for its 8 batches; the cross-wave reduce
        //    sums the 4 ks-slices -> full f=0..127 coverage per (r, batch).
        if (projb && lane < 32) {
            float xv[8];
#pragma unroll
            for (int b = 0; b < 8; ++b)
                xv[b] = inputs[((size_t)(bbase + b) * TT + t) * FF + fl];
#pragma unroll
            for (int r = 0; r < 8; ++r) {
                const float wv = sWin[r][fl];
#pragma unroll
                for (int b = 0; b < 8; ++b)
                    acc[r][b] = fmaf(wv, xv[b], acc[r][b]);
            }
        }

        // 3) Drain prefetch, pin ordering (rule #18), then MAC: W from
        //    registers, h from hbuf. 512 FMA/lane.
        wait_vm0();
        __builtin_amdgcn_sched_barrier(0);
#pragma unroll
        for (int r = 0; r < 8; ++r)
#pragma unroll
            for (int b = 0; b < 8; ++b) {
                float a = acc[r][b];
                a = fmaf(wreg[r][0].x, hbuf[b][0].x, a);
                a = fmaf(wreg[r][0].y, hbuf[b][0].y, a);
                a = fmaf(wreg[r][0].z, hbuf[b][0].z, a);
                a = fmaf(wreg[r][0].w, hbuf[b][0].w, a);
                a = fmaf(wreg[r][1].x, hbuf[b][1].x, a);
                a = fmaf(wreg[r][1].y, hbuf[b][1].y, a);
                a = fmaf(wreg[r][1].z, hbuf[b][1].z, a);
                a = fmaf(wreg[r][1].w, hbuf[b][1].w, a);
                acc[r][b] = a;
            }

        // 4) Fold 64 values -> 1/lane (R11-verified). Level d moves index-bit
        //    into lane-bit d; after d=32..1, lane L holds the full-wave sum
        //    for index i = L (i = r*8+b).
        float e;
        {
            float s32v[32];
#pragma unroll
            for (int i = 0; i < 32; ++i) {
                const float A  = acc[i >> 3][i & 7];
                const float Bv = acc[(i >> 3) + 4][i & 7];
                const float u  = __shfl_xor(A, 32);
                const float w2 = __shfl_xor(Bv, 32);
                s32v[i] = hi32 ? (Bv + w2) : (A + u);
            }
            float s16v[16];
#pragma unroll
            for (int i = 0; i < 16; ++i) {
                const float u  = __shfl_xor(s32v[i], 16);
                const float w2 = __shfl_xor(s32v[i + 16], 16);
                s16v[i] = hi16 ? (s32v[i + 16] + w2) : (s32v[i] + u);
            }
            float s8v[8];
#pragma unroll
            for (int i = 0; i < 8; ++i) {
                const float u  = __shfl_xor(s16v[i], 8);
                const float w2 = __shfl_xor(s16v[i + 8], 8);
                s8v[i] = hi8 ? (s16v[i + 8] + w2) : (s16v[i] + u);
            }
            float s4v[4];
#pragma unroll
            for (int i = 0; i < 4; ++i) {
                const float u  = __shfl_xor(s8v[i], 4);
                const float w2 = __shfl_xor(s8v[i + 4], 4);
                s4v[i] = hi4 ? (s8v[i + 4] + w2) : (s8v[i] + u);
            }
            float s2v[2];
#pragma unroll
            for (int i = 0; i < 2; ++i) {
                const float u  = __shfl_xor(s4v[i], 2);
                const float w2 = __shfl_xor(s4v[i + 2], 2);
                s2v[i] = hi2 ? (s4v[i + 2] + w2) : (s4v[i] + u);
            }
            const float u  = __shfl_xor(s2v[0], 1);
            const float w2 = __shfl_xor(s2v[1], 1);
            e = hi1 ? (s2v[1] + w2) : (s2v[0] + u);
        }

        // 5) Cross-wave reduce (4 k-slices per batch-group) + epilogue.
        sRed[wave][lane] = e;
        __syncthreads();
        if (tid < 128) {
            const float val = sRed[ebg][eL] + sRed[2 + ebg][eL] +
                              sRed[4 + ebg][eL] + sRed[6 + ebg][eL];
            const float pre  = val + myBias;
            const float vnew = 0.05f * hold + 0.95f * tanhf(pre);
            stg_sc1(hn, eOff, vnew);
            if (r0b >= HALFR)
                out[((size_t)eB * TT + t) * HALFR + (er - HALFR)] = vnew;
        }

        // 6) Drain stores, block-sync, R5 two-level all-relaxed grid barrier.
        wait_vm0();
        __syncthreads();
        if (tid == 0) {
            const unsigned tgt = (unsigned)(t + 1);
            const unsigned old = __hip_atomic_fetch_add(grpCnt, 1u, __ATOMIC_RELAXED,
                                                        __HIP_MEMORY_SCOPE_AGENT);
            if (old == tgt * 16u - 1u) {                   // last arriver in group
                const unsigned mo = __hip_atomic_fetch_add(masterCnt, 1u, __ATOMIC_RELAXED,
                                                           __HIP_MEMORY_SCOPE_AGENT);
                if (mo == tgt * 16u - 1u) {                // last group overall
                    __hip_atomic_store(masterEpoch, tgt, __ATOMIC_RELAXED,
                                       __HIP_MEMORY_SCOPE_AGENT);
                } else {
                    while (__hip_atomic_load(masterEpoch, __ATOMIC_RELAXED,
                                             __HIP_MEMORY_SCOPE_AGENT) < tgt)
                        __builtin_amdgcn_s_sleep(2);
                }
                __hip_atomic_store(grpEpoch, tgt, __ATOMIC_RELAXED,
                                   __HIP_MEMORY_SCOPE_AGENT);
            } else {
                while (__hip_atomic_load(grpEpoch, __ATOMIC_RELAXED,
                                         __HIP_MEMORY_SCOPE_AGENT) < tgt)
                    __builtin_amdgcn_s_sleep(2);
            }
        }
        __syncthreads();
    }
}

// ---------------- fallback path (proven R1): fp32, 1024 launches ----------------

__global__ void init_h_kernel(float* __restrict__ h, const float* __restrict__ start) {
    int idx = blockIdx.x * blockDim.x + threadIdx.x;
    if (idx < BB * RR) h[idx] = start[idx & (RR - 1)];
}

__global__ __launch_bounds__(512, 2) void step_kernel(
    const float* __restrict__ inputs, const float* __restrict__ Win,
    const float* __restrict__ Wrec, const float* __restrict__ bias,
    const float* __restrict__ h_cur, float* __restrict__ h_next,
    float* __restrict__ out, int t)
{
    const int tid  = threadIdx.x;
    const int wave = tid >> 6;
    const int half = (tid >> 5) & 1;
    const int kl   = tid & 31;
    const int b    = wave * 2 + half;
    const int r0   = blockIdx.x * 8;

    float acc[8];
#pragma unroll
    for (int r = 0; r < 8; ++r) acc[r] = 0.0f;

    if (r0 < HALFR) {
        const float4 in4 = *reinterpret_cast<const float4*>(
            inputs + ((size_t)b * TT + t) * FF + kl * 4);
#pragma unroll
        for (int r = 0; r < 8; ++r) {
            const float4 w4 = *reinterpret_cast<const float4*>(
                Win + (size_t)(r0 + r) * FF + kl * 4);
            acc[r] += in4.x * w4.x + in4.y * w4.y + in4.z * w4.z + in4.w * w4.w;
        }
    }

    const float* hb = h_cur + (size_t)b * RR;
#pragma unroll 2
    for (int j = 0; j < 16; ++j) {
        const int k = kl * 4 + j * 128;
        const float4 h4 = *reinterpret_cast<const float4*>(hb + k);
#pragma unroll
        for (int r = 0; r < 8; ++r) {
            const float4 w4 = *reinterpret_cast<const float4*>(
                Wrec + (size_t)(r0 + r) * RR + k);
            acc[r] = fmaf(h4.x, w4.x, acc[r]);
            acc[r] = fmaf(h4.y, w4.y, acc[r]);
            acc[r] = fmaf(h4.z, w4.z, acc[r]);
            acc[r] = fmaf(h4.w, w4.w, acc[r]);
        }
    }

#pragma unroll
    for (int r = 0; r < 8; ++r) {
        float v = acc[r];
        v += __shfl_xor(v, 1);  v += __shfl_xor(v, 2);
        v += __shfl_xor(v, 4);  v += __shfl_xor(v, 8);
        v += __shfl_xor(v, 16);
        acc[r] = v;
    }

    __shared__ float red[BB][8];
    if (kl == 0) {
#pragma unroll
        for (int r = 0; r < 8; ++r) red[b][r] = acc[r];
    }
    __syncthreads();

    if (tid < BB * 8) {
        const int rr = tid & 7, bb = tid >> 3;
        const int r  = r0 + rr;
        const float pre = red[bb][rr] + bias[r];
        const float h_old = h_cur[(size_t)bb * RR + r];
        const float hn = 0.05f * h_old + 0.95f * tanhf(pre);
        h_next[(size_t)bb * RR + r] = hn;
        if (r0 >= HALFR) out[((size_t)bb * TT + t) * HALFR + (r - HALFR)] = hn;
    }
}

// ---------------- launch ----------------

extern "C" void kernel_launch(void* const* d_in, const int* in_sizes, int n_in,
                              void* d_out, int out_size, void* d_ws, size_t ws_size,
                              hipStream_t stream) {
    const float* inputs = (const float*)d_in[0];   // [B,T,F]
    const float* Win    = (const float*)d_in[1];   // [R,F]
    const float* Wrec   = (const float*)d_in[2];   // [R,R]
    const float* bias   = (const float*)d_in[3];   // [R]
    const float* start  = (const float*)d_in[4];   // [R]
    float* out = (float*)d_out;                    // [B,T,HALFR]

    float* hA = (float*)d_ws;                      // [B,R] fp32
    float* hB = hA + (size_t)BB * RR;              // [B,R] fp32
    unsigned* bar = (unsigned*)(hB + (size_t)BB * RR);
    const size_t need = (size_t)BB * RR * 4 * 2 + 8192;

    if (ws_size >= need) {
        init_state_kernel<<<64, 512, 0, stream>>>(hA, start, bar);
        void* args[] = { (void*)&inputs, (void*)&Win, (void*)&Wrec, (void*)&bias,
                         (void*)&hA, (void*)&hB, (void*)&out, (void*)&bar };
        hipLaunchCooperativeKernel((void*)esn_f32, dim3(NBLK), dim3(NTHR),
                                   args, 0, stream);
    } else {
        init_h_kernel<<<(BB * RR + 255) / 256, 256, 0, stream>>>(hA, start);
        for (int t = 0; t < TT; ++t) {
            const float* hc = (t & 1) ? hB : hA;
            float*       hn = (t & 1) ? hA : hB;
            step_kernel<<<256, 512, 0, stream>>>(inputs, Win, Wrec, bias, hc, hn, out, t);
        }
    }
}

// Round 4
// 6371.748 us; speedup vs baseline: 3.4008x; 1.1941x over previous
//
#include <hip/hip_runtime.h>

#define BB 16
#define TT 1024
#define FF 128
#define RR 2048
#define HALFR 1024
#define NBLK 256
#define NTHR 512

// ---- coherent (IC-level) memory ops: bypass L1/L2, no fences needed ----
__device__ __forceinline__ float4 ldg_sc4(const float* base, unsigned voff) {
    float4 r;
    asm volatile("global_load_dwordx4 %0, %1, %2 sc0 sc1"
                 : "=v"(r) : "v"(voff), "s"(base) : "memory");
    return r;
}
__device__ __forceinline__ float ldg_sc1(const float* base, unsigned voff) {
    float r;
    asm volatile("global_load_dword %0, %1, %2 sc0 sc1"
                 : "=v"(r) : "v"(voff), "s"(base) : "memory");
    return r;
}
__device__ __forceinline__ void stg_sc1(float* base, unsigned voff, float v) {
    asm volatile("global_store_dword %0, %1, %2 sc0 sc1"
                 :: "v"(voff), "v"(v), "s"(base) : "memory");
}
__device__ __forceinline__ void wait_vm0() {
    asm volatile("s_waitcnt vmcnt(0)" ::: "memory");
}

// ---------------- init: h0 + barrier words ----------------
__global__ void init_state_kernel(float* __restrict__ h, const float* __restrict__ start,
                                  unsigned* __restrict__ bar) {
    int idx = blockIdx.x * blockDim.x + threadIdx.x;
    if (idx < BB * RR) h[idx] = start[idx & (RR - 1)];
    if (idx < 2048) bar[idx] = 0u;
}

// ---------------- persistent fp32 ESN kernel ----------------
// R14: batch-split broadcast halving on the R10 skeleton.
//  Insight: batches are INDEPENDENT recurrences. Grid = 2 batch-halves x
//  128 row-blocks: block (bg=bid&1, r0=(bid>>1)*16) computes 16 rows x 8
//  batches. Per-CU h read: 128KB -> 64KB/step; chip broadcast 32 -> 16
//  MB/step (the dominant cost — IC BW/latency, invisible to TCC counters).
//  Per-CU FMA unchanged (512/lane). W for 16 rows = 128KB in LDS (R13
//  proved LDS W-reads are free under VALU at 2 waves/SIMD; its register-W
//  + 126-shfl fold was a net LOSS — reverted).
//  Waves = 4 batch-pairs x 2 k-halves: every (b,k) read once per block.
//  Fold: 5 select-levels (lane-bits 5..1 <- index-bits 4..0) + 1 pure
//  butterfly (bit 0) = 63 shfl; lane L holds elem i=L>>1 (r=i>>1, b=i&1).
//  h path + barrier: byte-for-byte the proven R10/R13 mechanics (sc0sc1
//  loads, individual voffs, unconditional clamped hold, vmcnt0 +
//  sched_barrier(0), two-level all-relaxed global barrier).
__global__ __launch_bounds__(NTHR, 2) void esn_f32(
    const float* __restrict__ inputs,   // [B,T,F]
    const float* __restrict__ Win,      // [R,F]
    const float* __restrict__ Wrec,     // [R,R]
    const float* __restrict__ bias,     // [R]
    float* __restrict__ hA,             // [B,R]
    float* __restrict__ hB,             // [B,R]
    float* __restrict__ out,            // [B,T,HALFR]
    unsigned* __restrict__ bar)
{
    __shared__ __align__(16) float sW[16][RR];    // 128 KB
    __shared__ __align__(16) float sWin[16][FF];  // 8 KB
    __shared__ float sRed[8][32];                 // 1 KB

    const int tid  = threadIdx.x;
    const int lane = tid & 63;
    const int wave = tid >> 6;          // 0..7
    const int bp   = wave >> 1;         // batch-pair 0..3 (batches bp*2, bp*2+1)
    const int kh   = wave & 1;          // k-half: kh*1024 .. +1023
    const int bg   = blockIdx.x & 1;    // batch half: batches bg*8 .. bg*8+7
    const int r0   = (blockIdx.x >> 1) * 16;
    const int bbase = bg * 8;
    const bool projb = (r0 < HALFR);

    // Stage W (16 rows x 2048) + Win (16 rows x 128) into LDS once.
    {
        const float4* wsrc = (const float4*)(Wrec + (size_t)r0 * RR);
        float4* wdst = (float4*)sW;
        for (int i = tid; i < (16 * RR) / 4; i += NTHR) wdst[i] = wsrc[i];
        const float4* wis = (const float4*)(Win + (size_t)r0 * FF);
        float4* wid = (float4*)sWin;
        for (int i = tid; i < (16 * FF) / 4; i += NTHR) wid[i] = wis[i];
    }
    __syncthreads();

    const int khbase = kh * 1024;
    const int fl     = kh * 64 + lane;  // proj f: 2 kh-waves x 64 lanes cover f=0..127
    const bool hi32 = (lane & 32) != 0;
    const bool hi16 = (lane & 16) != 0;
    const bool hi8  = (lane & 8)  != 0;
    const bool hi4  = (lane & 4)  != 0;
    const bool hi2  = (lane & 2)  != 0;

    // Coherent h-load byte offsets: 8 individually precomputed (R10 style).
    unsigned voffH[2][4];
#pragma unroll
    for (int b2 = 0; b2 < 2; ++b2)
#pragma unroll
        for (int j = 0; j < 4; ++j)
            voffH[b2][j] = (unsigned)((((bbase + bp * 2 + b2) * RR)
                                       + khbase + j * 256 + lane * 4) * 4);

    // Epilogue mapping (tid < 128): bp_e = tid>>5, i = tid&31 -> elem
    // (r = i>>1, b2 = i&1). hold-load offset valid for ALL threads (clamped).
    const int bpE = (tid >> 5) & 3;
    const int iE  = tid & 31;
    const int er  = r0 + (iE >> 1);
    const int eB  = bbase + bpE * 2 + (iE & 1);
    const int eBc = (tid < 128) ? eB : 0;
    const float myBias = bias[er];
    const unsigned eOff = (unsigned)((eBc * RR + er) * 4);

    // R5 two-level barrier state (all-relaxed; each word on its own 128B line).
    const unsigned g = blockIdx.x & 15u;
    unsigned* grpCnt      = bar + g * 32;
    unsigned* masterCnt   = bar + 16 * 32;
    unsigned* masterEpoch = bar + 17 * 32;
    unsigned* grpEpoch    = bar + (18 + g) * 32;

    for (int t = 0; t < TT; ++t) {
        const float* hc = (t & 1) ? hB : hA;
        float*       hn = (t & 1) ? hA : hB;

        // 1) Issue ALL coherent h loads up front (8 + 1 in flight).
        float4 hbuf[2][4];
#pragma unroll
        for (int b2 = 0; b2 < 2; ++b2)
#pragma unroll
            for (int j = 0; j < 4; ++j)
                hbuf[b2][j] = ldg_sc4(hc, voffH[b2][j]);
        const float hold = ldg_sc1(hc, eOff);

        float acc[16][2];
#pragma unroll
        for (int r = 0; r < 16; ++r) {
            acc[r][0] = 0.0f; acc[r][1] = 0.0f;
        }

        // 2) Input projection overlaps h-load latency. All 64 lanes: wave
        //    (bp,kh) covers f = kh*64+lane for its 2 batches; kh-waves are
        //    summed by the cross-wave reduce -> full f coverage.
        if (projb) {
            float xv[2];
#pragma unroll
            for (int b2 = 0; b2 < 2; ++b2)
                xv[b2] = inputs[((size_t)(bbase + bp * 2 + b2) * TT + t) * FF + fl];
#pragma unroll
            for (int r = 0; r < 16; ++r) {
                const float wv = sWin[r][fl];
                acc[r][0] = fmaf(wv, xv[0], acc[r][0]);
                acc[r][1] = fmaf(wv, xv[1], acc[r][1]);
            }
        }

        // 3) Drain prefetch, pin ordering, then MAC: W from LDS, h from hbuf.
        //    64 ds_read_b128/lane/step (512 wave-insts/CU — R10-proven free),
        //    512 FMA/lane.
        wait_vm0();
        __builtin_amdgcn_sched_barrier(0);
#pragma unroll
        for (int j = 0; j < 4; ++j) {
            const int k = khbase + j * 256 + lane * 4;
            float4 wv[16];
#pragma unroll
            for (int r = 0; r < 16; ++r) wv[r] = *(const float4*)&sW[r][k];
#pragma unroll
            for (int r = 0; r < 16; ++r)
#pragma unroll
                for (int b2 = 0; b2 < 2; ++b2) {
                    float a = acc[r][b2];
                    a = fmaf(wv[r].x, hbuf[b2][j].x, a);
                    a = fmaf(wv[r].y, hbuf[b2][j].y, a);
                    a = fmaf(wv[r].z, hbuf[b2][j].z, a);
                    a = fmaf(wv[r].w, hbuf[b2][j].w, a);
                    acc[r][b2] = a;
                }
        }

        // 4) Fold 32 elems -> lane L holds elem i=L>>1, full 64-lane sum.
        //    5 select-levels (index bits 4..0 -> lane bits 5..1) + 1 pure
        //    butterfly on lane bit 0 (k within lane pairs).
        float e;
        {
            float s32v[16];
#pragma unroll
            for (int i = 0; i < 16; ++i) {
                const float A  = acc[i >> 1][i & 1];        // elem i
                const float Bv = acc[(i >> 1) + 8][i & 1];  // elem i+16
                const float u  = __shfl_xor(A, 32);
                const float w2 = __shfl_xor(Bv, 32);
                s32v[i] = hi32 ? (Bv + w2) : (A + u);
            }
            float s16v[8];
#pragma unroll
            for (int i = 0; i < 8; ++i) {
                const float u  = __shfl_xor(s32v[i], 16);
                const float w2 = __shfl_xor(s32v[i + 8], 16);
                s16v[i] = hi16 ? (s32v[i + 8] + w2) : (s32v[i] + u);
            }
            float s8v[4];
#pragma unroll
            for (int i = 0; i < 4; ++i) {
                const float u  = __shfl_xor(s16v[i], 8);
                const float w2 = __shfl_xor(s16v[i + 4], 8);
                s8v[i] = hi8 ? (s16v[i + 4] + w2) : (s16v[i] + u);
            }
            float s4v[2];
#pragma unroll
            for (int i = 0; i < 2; ++i) {
                const float u  = __shfl_xor(s8v[i], 4);
                const float w2 = __shfl_xor(s8v[i + 2], 4);
                s4v[i] = hi4 ? (s8v[i + 2] + w2) : (s8v[i] + u);
            }
            {
                const float u  = __shfl_xor(s4v[0], 2);
                const float w2 = __shfl_xor(s4v[1], 2);
                e = hi2 ? (s4v[1] + w2) : (s4v[0] + u);
            }
            e += __shfl_xor(e, 1);   // fold remaining lane bit 0
        }

        // 5) Cross-wave reduce (2 kh-waves per batch-pair) + epilogue.
        sRed[wave][lane >> 1] = e;   // lanes 2m,2m+1 hold identical e
        __syncthreads();
        if (tid < 128) {
            const float val = sRed[bpE * 2][iE] + sRed[bpE * 2 + 1][iE];
            const float pre  = val + myBias;
            const float vnew = 0.05f * hold + 0.95f * tanhf(pre);
            stg_sc1(hn, eOff, vnew);
            if (r0 >= HALFR)
                out[((size_t)eB * TT + t) * HALFR + (er - HALFR)] = vnew;
        }

        // 6) Drain stores, block-sync, R5 two-level all-relaxed grid barrier.
        wait_vm0();
        __syncthreads();
        if (tid == 0) {
            const unsigned tgt = (unsigned)(t + 1);
            const unsigned old = __hip_atomic_fetch_add(grpCnt, 1u, __ATOMIC_RELAXED,
                                                        __HIP_MEMORY_SCOPE_AGENT);
            if (old == tgt * 16u - 1u) {                   // last arriver in group
                const unsigned mo = __hip_atomic_fetch_add(masterCnt, 1u, __ATOMIC_RELAXED,
                                                           __HIP_MEMORY_SCOPE_AGENT);
                if (mo == tgt * 16u - 1u) {                // last group overall
                    __hip_atomic_store(masterEpoch, tgt, __ATOMIC_RELAXED,
                                       __HIP_MEMORY_SCOPE_AGENT);
                } else {
                    while (__hip_atomic_load(masterEpoch, __ATOMIC_RELAXED,
                                             __HIP_MEMORY_SCOPE_AGENT) < tgt)
                        __builtin_amdgcn_s_sleep(2);
                }
                __hip_atomic_store(grpEpoch, tgt, __ATOMIC_RELAXED,
                                   __HIP_MEMORY_SCOPE_AGENT);
            } else {
                while (__hip_atomic_load(grpEpoch, __ATOMIC_RELAXED,
                                         __HIP_MEMORY_SCOPE_AGENT) < tgt)
                    __builtin_amdgcn_s_sleep(2);
            }
        }
        __syncthreads();
    }
}

// ---------------- fallback path (proven R1): fp32, 1024 launches ----------------

__global__ void init_h_kernel(float* __restrict__ h, const float* __restrict__ start) {
    int idx = blockIdx.x * blockDim.x + threadIdx.x;
    if (idx < BB * RR) h[idx] = start[idx & (RR - 1)];
}

__global__ __launch_bounds__(512, 2) void step_kernel(
    const float* __restrict__ inputs, const float* __restrict__ Win,
    const float* __restrict__ Wrec, const float* __restrict__ bias,
    const float* __restrict__ h_cur, float* __restrict__ h_next,
    float* __restrict__ out, int t)
{
    const int tid  = threadIdx.x;
    const int wave = tid >> 6;
    const int half = (tid >> 5) & 1;
    const int kl   = tid & 31;
    const int b    = wave * 2 + half;
    const int r0   = blockIdx.x * 8;

    float acc[8];
#pragma unroll
    for (int r = 0; r < 8; ++r) acc[r] = 0.0f;

    if (r0 < HALFR) {
        const float4 in4 = *reinterpret_cast<const float4*>(
            inputs + ((size_t)b * TT + t) * FF + kl * 4);
#pragma unroll
        for (int r = 0; r < 8; ++r) {
            const float4 w4 = *reinterpret_cast<const float4*>(
                Win + (size_t)(r0 + r) * FF + kl * 4);
            acc[r] += in4.x * w4.x + in4.y * w4.y + in4.z * w4.z + in4.w * w4.w;
        }
    }

    const float* hb = h_cur + (size_t)b * RR;
#pragma unroll 2
    for (int j = 0; j < 16; ++j) {
        const int k = kl * 4 + j * 128;
        const float4 h4 = *reinterpret_cast<const float4*>(hb + k);
#pragma unroll
        for (int r = 0; r < 8; ++r) {
            const float4 w4 = *reinterpret_cast<const float4*>(
                Wrec + (size_t)(r0 + r) * RR + k);
            acc[r] = fmaf(h4.x, w4.x, acc[r]);
            acc[r] = fmaf(h4.y, w4.y, acc[r]);
            acc[r] = fmaf(h4.z, w4.z, acc[r]);
            acc[r] = fmaf(h4.w, w4.w, acc[r]);
        }
    }

#pragma unroll
    for (int r = 0; r < 8; ++r) {
        float v = acc[r];
        v += __shfl_xor(v, 1);  v += __shfl_xor(v, 2);
        v += __shfl_xor(v, 4);  v += __shfl_xor(v, 8);
        v += __shfl_xor(v, 16);
        acc[r] = v;
    }

    __shared__ float red[BB][8];
    if (kl == 0) {
#pragma unroll
        for (int r = 0; r < 8; ++r) red[b][r] = acc[r];
    }
    __syncthreads();

    if (tid < BB * 8) {
        const int rr = tid & 7, bb = tid >> 3;
        const int r  = r0 + rr;
        const float pre = red[bb][rr] + bias[r];
        const float h_old = h_cur[(size_t)bb * RR + r];
        const float hn = 0.05f * h_old + 0.95f * tanhf(pre);
        h_next[(size_t)bb * RR + r] = hn;
        if (r0 >= HALFR) out[((size_t)bb * TT + t) * HALFR + (r - HALFR)] = hn;
    }
}

// ---------------- launch ----------------

extern "C" void kernel_launch(void* const* d_in, const int* in_sizes, int n_in,
                              void* d_out, int out_size, void* d_ws, size_t ws_size,
                              hipStream_t stream) {
    const float* inputs = (const float*)d_in[0];   // [B,T,F]
    const float* Win    = (const float*)d_in[1];   // [R,F]
    const float* Wrec   = (const float*)d_in[2];   // [R,R]
    const float* bias   = (const float*)d_in[3];   // [R]
    const float* start  = (const float*)d_in[4];   // [R]
    float* out = (float*)d_out;                    // [B,T,HALFR]

    float* hA = (float*)d_ws;                      // [B,R] fp32
    float* hB = hA + (size_t)BB * RR;              // [B,R] fp32
    unsigned* bar = (unsigned*)(hB + (size_t)BB * RR);
    const size_t need = (size_t)BB * RR * 4 * 2 + 8192;

    if (ws_size >= need) {
        init_state_kernel<<<64, 512, 0, stream>>>(hA, start, bar);
        void* args[] = { (void*)&inputs, (void*)&Win, (void*)&Wrec, (void*)&bias,
                         (void*)&hA, (void*)&hB, (void*)&out, (void*)&bar };
        hipLaunchCooperativeKernel((void*)esn_f32, dim3(NBLK), dim3(NTHR),
                                   args, 0, stream);
    } else {
        init_h_kernel<<<(BB * RR + 255) / 256, 256, 0, stream>>>(hA, start);
        for (int t = 0; t < TT; ++t) {
            const float* hc = (t & 1) ? hB : hA;
            float*       hn = (t & 1) ? hA : hB;
            step_kernel<<<256, 512, 0, stream>>>(inputs, Win, Wrec, bias, hc, hn, out, t);
        }
    }
}